// Round 10
// baseline (47.777 us; speedup 1.0000x reference)
//
#include <hip/hip_runtime.h>
#include <hip/hip_bf16.h>

typedef __attribute__((ext_vector_type(8))) short short8_t;
typedef __attribute__((ext_vector_type(4))) float f32x4;

static __device__ __forceinline__ unsigned short f2bf(float f) {
    unsigned int u = __float_as_uint(f);
    unsigned int r = u + 0x7fffu + ((u >> 16) & 1u);   // RNE (finite inputs)
    return (unsigned short)(r >> 16);
}

#define BM 128
#define BN 64
#define LDA 136   // bf16 elems per LDS row: 128 + 8 pad
#define REPS 4    // DIAGNOSTIC: repeat whole body so our dispatch outlasts the
                  // 40us harness fills and shows up in rocprof top-5.

__global__ __launch_bounds__(256) void fused_kernel(
        const float* __restrict__ X,   // [8192][128] f32
        const float* __restrict__ P,   // [1000][128] f32
        float* __restrict__ out) {     // [8192][1000] f32
    __shared__ unsigned short As[BM][LDA];
    __shared__ unsigned short Bs[BN][LDA];
    __shared__ float xq_s[BM];
    __shared__ float pq_s[BN];

    int t = threadIdx.x;
    int bn = blockIdx.x & 15;
    int bm = blockIdx.x >> 4;
    const int rowA0 = bm * BM;
    const int rowB0 = bn * BN;

    #pragma unroll 1
    for (int rep = 0; rep < REPS; ++rep) {
        #pragma unroll
        for (int it = 0; it < 8; ++it) {
            int idx = it * 256 + t;
            int r = idx >> 4;
            int c8 = (idx & 15) * 8;
            const float4* src = reinterpret_cast<const float4*>(X + (size_t)(rowA0 + r) * 128 + c8);
            float4 v0 = src[0], v1 = src[1];
            short8_t b;
            b[0] = (short)f2bf(v0.x); b[1] = (short)f2bf(v0.y);
            b[2] = (short)f2bf(v0.z); b[3] = (short)f2bf(v0.w);
            b[4] = (short)f2bf(v1.x); b[5] = (short)f2bf(v1.y);
            b[6] = (short)f2bf(v1.z); b[7] = (short)f2bf(v1.w);
            *reinterpret_cast<short8_t*>(&As[r][c8]) = b;
            float s = v0.x*v0.x + v0.y*v0.y + v0.z*v0.z + v0.w*v0.w
                    + v1.x*v1.x + v1.y*v1.y + v1.z*v1.z + v1.w*v1.w;
            s += __shfl_xor(s, 1, 64);
            s += __shfl_xor(s, 2, 64);
            s += __shfl_xor(s, 4, 64);
            s += __shfl_xor(s, 8, 64);
            if ((t & 15) == 0) xq_s[r] = s;
        }
        #pragma unroll
        for (int it = 0; it < 4; ++it) {
            int idx = it * 256 + t;
            int r = idx >> 4;
            int c8 = (idx & 15) * 8;
            int gr = rowB0 + r;
            float4 v0 = make_float4(0.f, 0.f, 0.f, 0.f);
            float4 v1 = make_float4(0.f, 0.f, 0.f, 0.f);
            if (gr < 1000) {
                const float4* src = reinterpret_cast<const float4*>(P + (size_t)gr * 128 + c8);
                v0 = src[0]; v1 = src[1];
            }
            short8_t b;
            b[0] = (short)f2bf(v0.x); b[1] = (short)f2bf(v0.y);
            b[2] = (short)f2bf(v0.z); b[3] = (short)f2bf(v0.w);
            b[4] = (short)f2bf(v1.x); b[5] = (short)f2bf(v1.y);
            b[6] = (short)f2bf(v1.z); b[7] = (short)f2bf(v1.w);
            *reinterpret_cast<short8_t*>(&Bs[r][c8]) = b;
            float s = v0.x*v0.x + v0.y*v0.y + v0.z*v0.z + v0.w*v0.w
                    + v1.x*v1.x + v1.y*v1.y + v1.z*v1.z + v1.w*v1.w;
            s += __shfl_xor(s, 1, 64);
            s += __shfl_xor(s, 2, 64);
            s += __shfl_xor(s, 4, 64);
            s += __shfl_xor(s, 8, 64);
            if ((t & 15) == 0) pq_s[r] = s;
        }
        __syncthreads();

        int wave = t >> 6;
        int lane = t & 63;
        int wm = (wave >> 1) * 64;
        int wn = (wave & 1) * 32;
        int lr = lane & 15;
        int lk = (lane >> 4) * 8;

        f32x4 acc[4][2] = {};
        #pragma unroll
        for (int ks = 0; ks < 4; ++ks) {
            int k0 = ks * 32 + lk;
            short8_t a[4], b[2];
            #pragma unroll
            for (int mi = 0; mi < 4; ++mi)
                a[mi] = *reinterpret_cast<const short8_t*>(&As[wm + mi * 16 + lr][k0]);
            #pragma unroll
            for (int ni = 0; ni < 2; ++ni)
                b[ni] = *reinterpret_cast<const short8_t*>(&Bs[wn + ni * 16 + lr][k0]);
            #pragma unroll
            for (int mi = 0; mi < 4; ++mi)
                #pragma unroll
                for (int ni = 0; ni < 2; ++ni)
                    acc[mi][ni] = __builtin_amdgcn_mfma_f32_16x16x32_bf16(
                            a[mi], b[ni], acc[mi][ni], 0, 0, 0);
        }

        int mrow_base = (lane >> 4) * 4;
        #pragma unroll
        for (int mi = 0; mi < 4; ++mi) {
            #pragma unroll
            for (int ni = 0; ni < 2; ++ni) {
                int cl = wn + ni * 16 + lr;
                int c = rowB0 + cl;
                if (c < 1000) {
                    float pq = pq_s[cl];
                    #pragma unroll
                    for (int j = 0; j < 4; ++j) {
                        int ml = wm + mi * 16 + mrow_base + j;
                        int m = rowA0 + ml;
                        out[(size_t)m * 1000 + c] = 2.f * acc[mi][ni][j] - xq_s[ml] - pq;
                    }
                }
            }
        }
        __syncthreads();   // LDS reuse across reps
    }
}

extern "C" void kernel_launch(void* const* d_in, const int* in_sizes, int n_in,
                              void* d_out, int out_size, void* d_ws, size_t ws_size,
                              hipStream_t stream) {
    const float* x = (const float*)d_in[0];   // (8192, 128) f32
    const float* p = (const float*)d_in[1];   // (1000, 128) f32
    float* out = (float*)d_out;               // (8192, 1000) f32
    (void)d_ws; (void)ws_size;
    fused_kernel<<<1024, 256, 0, stream>>>(x, p, out);
}

// Round 12
// 26.990 us; speedup vs baseline: 1.7702x; 1.7702x over previous
//
#include <hip/hip_runtime.h>
#include <hip/hip_bf16.h>

typedef __attribute__((ext_vector_type(8))) short short8_t;
typedef __attribute__((ext_vector_type(4))) float f32x4;

static __device__ __forceinline__ unsigned short f2bf(float f) {
    unsigned int u = __float_as_uint(f);
    unsigned int r = u + 0x7fffu + ((u >> 16) & 1u);   // RNE (finite inputs)
    return (unsigned short)(r >> 16);
}

// Convert f32 [rows_valid][128] -> bf16 [rows_total][128] (zero-padded), plus f32 row norms.
__global__ __launch_bounds__(256) void prep_kernel(
        const float* __restrict__ src, unsigned short* __restrict__ dst,
        float* __restrict__ sq, int rows_valid, int rows_total) {
    int t = threadIdx.x;
    int row = blockIdx.x * 8 + (t >> 5);
    int lane32 = t & 31;
    if (row >= rows_total) return;
    float4 v = make_float4(0.f, 0.f, 0.f, 0.f);
    if (row < rows_valid)
        v = reinterpret_cast<const float4*>(src + (size_t)row * 128)[lane32];
    ushort4 b;
    b.x = f2bf(v.x); b.y = f2bf(v.y); b.z = f2bf(v.z); b.w = f2bf(v.w);
    reinterpret_cast<ushort4*>(dst + (size_t)row * 128)[lane32] = b;
    float s = v.x*v.x + v.y*v.y + v.z*v.z + v.w*v.w;
    #pragma unroll
    for (int m = 16; m >= 1; m >>= 1) s += __shfl_xor(s, m, 64);
    if (lane32 == 0) sq[row] = s;
}

#define LDA 136   // 272B LDS row stride; frag reads <=4-way (free/cheap per m136)

// SWAPPED-OPERAND GEMM: D[class][sample] = mfma(P_frag, X_frag).
// D row dim ((lane>>4)*4+j) = classes -> thread holds 4 CONSECUTIVE classes for
// one sample -> epilogue = one float4 store per acc tile (wide, few transactions).
// Block: 64 samples x 128 classes. 1024 blocks, 256 thr, ~50.7KB LDS -> 3 blk/CU.
__global__ __launch_bounds__(256) void gemm_kernel(
        const unsigned short* __restrict__ Xb,   // [8192][128] bf16 bits
        const unsigned short* __restrict__ Pb,   // [1024][128] bf16 bits (pad rows 0)
        const float* __restrict__ xsq,           // [8192]
        const float* __restrict__ psq,           // [1024] (pad 0)
        float* __restrict__ out) {               // [8192][1000] f32
    __shared__ unsigned short Ps[128][LDA];      // classes x K
    __shared__ unsigned short Xs[64][LDA];       // samples x K
    __shared__ float xq_s[64];
    __shared__ float pq_s[128];

    const int t = threadIdx.x;
    // XCD-chunked swizzle: xcd = wg&7; each XCD gets 16 sample-tiles x 8 class-tiles
    // -> unique X 256KB + P 256KB per XCD L2.
    const int wg  = blockIdx.x;
    const int idx = wg >> 3;
    const int sample_tile = (wg & 7) * 16 + (idx >> 3);   // 0..127
    const int class_tile  = idx & 7;                       // 0..7
    const int n0 = sample_tile * 64;
    const int c0 = class_tile * 128;

    // ---- stage P tile: 128 rows x 128 bf16, 2 threads/row x 64 elems ----
    {
        int r = t >> 1, cb = (t & 1) * 64;
        const short8_t* src = reinterpret_cast<const short8_t*>(
                Pb + (size_t)(c0 + r) * 128 + cb);
        short8_t v0 = src[0], v1 = src[1], v2 = src[2], v3 = src[3];
        short8_t v4 = src[4], v5 = src[5], v6 = src[6], v7 = src[7];
        short8_t* dst = reinterpret_cast<short8_t*>(&Ps[r][cb]);
        dst[0] = v0; dst[1] = v1; dst[2] = v2; dst[3] = v3;
        dst[4] = v4; dst[5] = v5; dst[6] = v6; dst[7] = v7;
    }
    // ---- stage X tile: 64 rows x 128 bf16, 4 threads/row x 32 elems ----
    {
        int r = t >> 2, cb = (t & 3) * 32;
        const short8_t* src = reinterpret_cast<const short8_t*>(
                Xb + (size_t)(n0 + r) * 128 + cb);
        short8_t v0 = src[0], v1 = src[1], v2 = src[2], v3 = src[3];
        short8_t* dst = reinterpret_cast<short8_t*>(&Xs[r][cb]);
        dst[0] = v0; dst[1] = v1; dst[2] = v2; dst[3] = v3;
    }
    if (t < 64)  xq_s[t] = xsq[n0 + t];
    if (t < 128) pq_s[t] = psq[c0 + t];
    __syncthreads();

    const int wave = t >> 6;
    const int lane = t & 63;
    const int wc  = (wave >> 1) * 64;    // class group: 0 / 64   (4 tiles of 16)
    const int wsm = (wave & 1) * 32;     // sample group: 0 / 32  (2 tiles of 16)
    const int lr  = lane & 15;
    const int lkb = (lane >> 4) * 8;
    const int rb4 = (lane >> 4) * 4;     // class quad base within 16

    f32x4 acc[4][2] = {};
    #pragma unroll
    for (int ks = 0; ks < 4; ++ks) {
        int k0 = ks * 32 + lkb;
        short8_t a[4], b[2];
        #pragma unroll
        for (int ci = 0; ci < 4; ++ci)
            a[ci] = *reinterpret_cast<const short8_t*>(&Ps[wc + ci * 16 + lr][k0]);
        #pragma unroll
        for (int si = 0; si < 2; ++si)
            b[si] = *reinterpret_cast<const short8_t*>(&Xs[wsm + si * 16 + lr][k0]);
        #pragma unroll
        for (int ci = 0; ci < 4; ++ci)
            #pragma unroll
            for (int si = 0; si < 2; ++si)
                acc[ci][si] = __builtin_amdgcn_mfma_f32_16x16x32_bf16(
                        a[ci], b[si], acc[ci][si], 0, 0, 0);
    }

    // Epilogue: thread holds classes {cb..cb+3} for sample n -> float4 store.
    #pragma unroll
    for (int si = 0; si < 2; ++si) {
        int sl = wsm + si * 16 + lr;         // sample within block
        float xq = xq_s[sl];
        size_t gbase = (size_t)(n0 + sl) * 1000;
        #pragma unroll
        for (int ci = 0; ci < 4; ++ci) {
            int clb = wc + ci * 16 + rb4;    // class quad base within block
            int cb = c0 + clb;               // global class base (mult of 4)
            if (cb < 1000) {                 // 1000 % 4 == 0 -> exact guard
                float4 pq = *reinterpret_cast<const float4*>(&pq_s[clb]);
                f32x4 av = acc[ci][si];
                float4 o = make_float4(2.f * av[0] - pq.x - xq,
                                       2.f * av[1] - pq.y - xq,
                                       2.f * av[2] - pq.z - xq,
                                       2.f * av[3] - pq.w - xq);
                *reinterpret_cast<float4*>(out + gbase + cb) = o;
            }
        }
    }
}

// Correct-but-slow fallback.
__global__ __launch_bounds__(256) void naive_kernel(
        const float* __restrict__ x, const float* __restrict__ p,
        float* __restrict__ out) {
    long long idx = (long long)blockIdx.x * 256 + threadIdx.x;
    if (idx >= (long long)8192 * 1000) return;
    int n = (int)(idx / 1000);
    int c = (int)(idx % 1000);
    const float4* xr = reinterpret_cast<const float4*>(x + (size_t)n * 128);
    const float4* pr = reinterpret_cast<const float4*>(p + (size_t)c * 128);
    float d = 0.f;
    #pragma unroll
    for (int i = 0; i < 32; ++i) {
        float4 a = xr[i], b = pr[i];
        float dx = a.x - b.x, dy = a.y - b.y, dz = a.z - b.z, dw = a.w - b.w;
        d += dx * dx + dy * dy + dz * dz + dw * dw;
    }
    out[idx] = -d;
}

extern "C" void kernel_launch(void* const* d_in, const int* in_sizes, int n_in,
                              void* d_out, int out_size, void* d_ws, size_t ws_size,
                              hipStream_t stream) {
    const float* x = (const float*)d_in[0];   // (8192, 128) f32
    const float* p = (const float*)d_in[1];   // (1000, 128) f32
    float* out = (float*)d_out;               // (8192, 1000) f32

    const size_t xb_elems = (size_t)8192 * 128;
    const size_t pb_elems = (size_t)1024 * 128;
    const size_t need = xb_elems * 2 + pb_elems * 2 + 8192 * 4 + 1024 * 4;

    if (ws_size >= need) {
        unsigned short* xb = (unsigned short*)d_ws;
        unsigned short* pb = xb + xb_elems;
        float* xsq = (float*)(pb + pb_elems);
        float* psq = xsq + 8192;
        prep_kernel<<<1024, 256, 0, stream>>>(x, xb, xsq, 8192, 8192);
        prep_kernel<<<128, 256, 0, stream>>>(p, pb, psq, 1000, 1024);
        gemm_kernel<<<1024, 256, 0, stream>>>(xb, pb, xsq, psq, out);
    } else {
        naive_kernel<<<((size_t)8192 * 1000 + 255) / 256, 256, 0, stream>>>(x, p, out);
    }
}